// Round 1
// baseline (1960.484 us; speedup 1.0000x reference)
//
#include <hip/hip_runtime.h>
#include <math.h>

#define BB 16
#define HH 32
#define DD 128
#define HALF 64

// One block per (b,h). 256 threads = 8 groups of 32 lanes.
// Each group streams kv rows g, g+8, ... with online softmax.
__global__ __launch_bounds__(256, 4)
void decode_attn(const float* __restrict__ q,
                 const float* __restrict__ k,
                 const float* __restrict__ v,
                 const float* __restrict__ cache_k,
                 const float* __restrict__ cache_v,
                 const int* __restrict__ past_len_p,
                 float* __restrict__ out,
                 int past_cache)
{
    const int bh  = blockIdx.x;
    const int b   = bh / HH;
    const int h   = bh % HH;
    const int tid = threadIdx.x;
    const int g   = tid >> 5;   // group 0..7
    const int r   = tid & 31;   // lane within group

    __shared__ __align__(16) float s_qr[DD];
    __shared__ __align__(16) float s_kr[DD];
    __shared__ __align__(16) float s_o[8][DD];
    __shared__ float s_m[8];
    __shared__ float s_l[8];

    const int past = past_len_p[0];               // 4095
    // number of cache positions that are valid (kv_pos <= past)
    const int pc = min(past + 1, past_cache);     // = 4095 here

    // ---- RoPE for this (b,h)'s q and new-token k (one-time) ----
    const float* qp = q + (size_t)(b * HH + h) * DD;
    const float* kp = k + (size_t)(b * HH + h) * DD;
    if (tid < HALF) {
        int i = tid;
        // inv_freq in fp32 (mirrors reference fp32 value), angle product in fp32,
        // then precise sincos of that fp32 angle (large-arg range reduction).
        float inv_freq = (float)pow(10000.0, -(double)i / (double)HALF);
        float ang = (float)past * inv_freq;
        double ad = (double)ang;
        float c = (float)cos(ad);
        float s = (float)sin(ad);
        float q1 = qp[i], q2 = qp[i + HALF];
        s_qr[i]        = q1 * c - q2 * s;
        s_qr[i + HALF] = q2 * c + q1 * s;
        float k1 = kp[i], k2 = kp[i + HALF];
        s_kr[i]        = k1 * c - k2 * s;
        s_kr[i + HALF] = k2 * c + k1 * s;
    }
    __syncthreads();

    const float scale = 0.08838834764831845f;  // 1/sqrt(128)
    const float4 qf = ((const float4*)s_qr)[r];

    float  m = -1e30f, l = 0.f;
    float4 o = make_float4(0.f, 0.f, 0.f, 0.f);

    // ---- group 7 additionally processes the new (roped) token ----
    if (g == 7) {
        float4 kf = ((const float4*)s_kr)[r];
        float4 vf = *(const float4*)(v + (size_t)(b * HH + h) * DD + r * 4);
        float p = qf.x * kf.x + qf.y * kf.y + qf.z * kf.z + qf.w * kf.w;
        #pragma unroll
        for (int off = 16; off >= 1; off >>= 1) p += __shfl_xor(p, off);
        float s = p * scale;
        m = s; l = 1.f;
        o = vf;
    }

    // ---- main stream over cache positions ----
    const size_t row = (size_t)HH * DD;                 // 4096 floats between kv rows
    const size_t bstr = (size_t)past_cache * row;
    const float* kb = cache_k + (size_t)b * bstr + (size_t)h * DD + r * 4;
    const float* vb = cache_v + (size_t)b * bstr + (size_t)h * DD + r * 4;

    int kpos = g;
    float4 kf_n, vf_n;
    if (kpos < pc) {
        kf_n = *(const float4*)(kb + (size_t)kpos * row);
        vf_n = *(const float4*)(vb + (size_t)kpos * row);
    }
    for (; kpos < pc; kpos += 8) {
        float4 kf = kf_n, vf = vf_n;
        int nxt = kpos + 8;
        if (nxt < pc) {
            kf_n = *(const float4*)(kb + (size_t)nxt * row);
            vf_n = *(const float4*)(vb + (size_t)nxt * row);
        }
        float p = qf.x * kf.x + qf.y * kf.y + qf.z * kf.z + qf.w * kf.w;
        #pragma unroll
        for (int off = 16; off >= 1; off >>= 1) p += __shfl_xor(p, off);
        float s = p * scale;
        float nm  = fmaxf(m, s);
        float fac = __expf(m - nm);
        float pe  = __expf(s - nm);
        l = l * fac + pe;
        o.x = o.x * fac + pe * vf.x;
        o.y = o.y * fac + pe * vf.y;
        o.z = o.z * fac + pe * vf.z;
        o.w = o.w * fac + pe * vf.w;
        m = nm;
    }

    // ---- merge the 8 groups ----
    if (r == 0) { s_m[g] = m; s_l[g] = l; }
    *(float4*)&s_o[g][r * 4] = o;
    __syncthreads();

    if (tid < DD) {
        float mt = -1e30f;
        #pragma unroll
        for (int i = 0; i < 8; i++) mt = fmaxf(mt, s_m[i]);
        float lt = 0.f, acc = 0.f;
        #pragma unroll
        for (int i = 0; i < 8; i++) {
            float w = __expf(s_m[i] - mt);
            lt += s_l[i] * w;
            acc += s_o[i][tid] * w;
        }
        out[(size_t)b * (HH * DD) + h * DD + tid] = acc / lt;
    }
}

extern "C" void kernel_launch(void* const* d_in, const int* in_sizes, int n_in,
                              void* d_out, int out_size, void* d_ws, size_t ws_size,
                              hipStream_t stream) {
    const float* q  = (const float*)d_in[0];
    const float* k  = (const float*)d_in[1];
    const float* v  = (const float*)d_in[2];
    const float* ck = (const float*)d_in[3];
    const float* cv = (const float*)d_in[4];
    const int*   pl = (const int*)d_in[5];
    float* out = (float*)d_out;
    int past_cache = in_sizes[3] / (BB * HH * DD);  // 4095
    decode_attn<<<dim3(BB * HH), dim3(256), 0, stream>>>(q, k, v, ck, cv, pl, out, past_cache);
}